// Round 2
// baseline (624.888 us; speedup 1.0000x reference)
//
#include <hip/hip_runtime.h>
#include <math.h>

// Problem constants (from reference): B=32, C=D=64, H=W=64, K=1024
constexpr int K_CODES = 1024;
constexpr int D_DIM   = 64;
constexpr int HW      = 64 * 64;          // 4096
constexpr int NPOS    = 32 * HW;          // 131072 positions
constexpr int CHW     = D_DIM * HW;       // 262144 (per-batch stride)

// ws layout (floats): [0..1023] c2 (codebook squared norms), [1024..2047] histogram
__global__ void vq_prep(const float* __restrict__ cb, float* __restrict__ ws) {
    int k = blockIdx.x * blockDim.x + threadIdx.x;
    if (k < K_CODES) {
        const float4* row = reinterpret_cast<const float4*>(cb + k * D_DIM);
        float s0 = 0.f, s1 = 0.f, s2 = 0.f, s3 = 0.f;
#pragma unroll
        for (int i = 0; i < 16; ++i) {
            float4 v = row[i];
            s0 = fmaf(v.x, v.x, s0);
            s1 = fmaf(v.y, v.y, s1);
            s2 = fmaf(v.z, v.z, s2);
            s3 = fmaf(v.w, v.w, s3);
        }
        ws[k] = (s0 + s1) + (s2 + s3);
        ws[K_CODES + k] = 0.0f;
    }
}

// main kernel: one thread per spatial position.
// __launch_bounds__(256, 1): min 1 wave/EU -> VGPR budget up to 512, so the
// 64-float x vector stays register-resident (round 1 spilled at VGPR=56).
__global__ __launch_bounds__(256, 1) void vq_main(
    const float* __restrict__ in, const float* __restrict__ cb,
    float* __restrict__ out, float* __restrict__ ws) {
    const float* __restrict__ c2 = ws;
    float* hist = ws + K_CODES;

    int n  = blockIdx.x * 256 + threadIdx.x;   // n = b*HW + hw
    int b  = n >> 12;                          // / 4096
    int hw = n & 4095;
    const float* xb = in + (size_t)b * CHW + hw;

    // load x[c] (strided per-thread, coalesced across lanes for each c)
    float x[D_DIM];
#pragma unroll
    for (int c = 0; c < D_DIM; ++c) x[c] = xb[(size_t)c * HW];

    // x2 = sum x^2 (4 partials) — same ordering as round 1 (matched np exactly)
    float s0 = 0.f, s1 = 0.f, s2 = 0.f, s3 = 0.f;
#pragma unroll
    for (int c = 0; c < D_DIM; c += 4) {
        s0 = fmaf(x[c + 0], x[c + 0], s0);
        s1 = fmaf(x[c + 1], x[c + 1], s1);
        s2 = fmaf(x[c + 2], x[c + 2], s2);
        s3 = fmaf(x[c + 3], x[c + 3], s3);
    }
    float x2 = (s0 + s1) + (s2 + s3);

    float best = INFINITY;
    int   bidx = 0;
#pragma unroll 4
    for (int k = 0; k < K_CODES; ++k) {
        // wave-uniform address -> scalarized s_load of the codebook row
        const float4* crow = reinterpret_cast<const float4*>(cb + k * D_DIM);
        float d0 = 0.f, d1 = 0.f, d2 = 0.f, d3 = 0.f;
#pragma unroll
        for (int i = 0; i < 16; ++i) {
            float4 v = crow[i];
            d0 = fmaf(x[4 * i + 0], v.x, d0);
            d1 = fmaf(x[4 * i + 1], v.y, d1);
            d2 = fmaf(x[4 * i + 2], v.z, d2);
            d3 = fmaf(x[4 * i + 3], v.w, d3);
        }
        float dot  = (d0 + d1) + (d2 + d3);
        float dist = (x2 - 2.0f * dot) + c2[k];
        bool m = dist < best;          // strict < keeps first index on ties
        best = m ? dist : best;
        bidx = m ? k : bidx;
    }

    // quantized = x + (q - x), written NCHW (coalesced per channel)
    float* ob = out + (size_t)b * CHW + hw;
    const float* __restrict__ q = cb + bidx * D_DIM;
#pragma unroll
    for (int c = 0; c < D_DIM; ++c) {
        float qc = q[c];
        ob[(size_t)c * HW] = x[c] + (qc - x[c]);
    }

    atomicAdd(&hist[bidx], 1.0f);
}

// perplexity: one block, 1024 threads (16 waves)
__global__ void vq_ppl(const float* __restrict__ ws, float* __restrict__ outp) {
    __shared__ float red[16];
    int t = threadIdx.x;
    float e = ws[K_CODES + t] * (1.0f / (float)NPOS);
    float term = e * logf(e + 1e-10f);
#pragma unroll
    for (int off = 32; off > 0; off >>= 1)
        term += __shfl_down(term, off, 64);
    int lane = t & 63, wid = t >> 6;
    if (lane == 0) red[wid] = term;
    __syncthreads();
    if (t == 0) {
        float s = 0.f;
#pragma unroll
        for (int i = 0; i < 16; ++i) s += red[i];
        *outp = expf(-s);
    }
}

extern "C" void kernel_launch(void* const* d_in, const int* in_sizes, int n_in,
                              void* d_out, int out_size, void* d_ws, size_t ws_size,
                              hipStream_t stream) {
    const float* in = (const float*)d_in[0];   // [32,64,64,64] fp32
    const float* cb = (const float*)d_in[1];   // [1024,64] fp32
    float* out = (float*)d_out;                // quantized [8388608] + ppl [1]
    float* ws  = (float*)d_ws;

    vq_prep<<<4, 256, 0, stream>>>(cb, ws);
    vq_main<<<NPOS / 256, 256, 0, stream>>>(in, cb, out, ws);
    vq_ppl<<<1, 1024, 0, stream>>>(ws, out + (size_t)8388608);
}

// Round 4
// 619.521 us; speedup vs baseline: 1.0087x; 1.0087x over previous
//
#include <hip/hip_runtime.h>
#include <math.h>

// Problem constants (from reference): B=32, C=D=64, H=W=64, K=1024
constexpr int K_CODES = 1024;
constexpr int D_DIM   = 64;
constexpr int HW      = 64 * 64;          // 4096
constexpr int NPOS    = 32 * HW;          // 131072 positions
constexpr int CHW     = D_DIM * HW;       // 262144 (per-batch stride)

typedef float f32x16 __attribute__((ext_vector_type(16)));

#define REPEAT16(M) M(0) M(1) M(2) M(3) M(4) M(5) M(6) M(7) \
                    M(8) M(9) M(10) M(11) M(12) M(13) M(14) M(15)

// ws layout (floats): [0..1023] c2 (codebook squared norms), [1024..2047] histogram
__global__ void vq_prep(const float* __restrict__ cb, float* __restrict__ ws) {
    int k = blockIdx.x * blockDim.x + threadIdx.x;
    if (k < K_CODES) {
        const float4* row = reinterpret_cast<const float4*>(cb + k * D_DIM);
        float s0 = 0.f, s1 = 0.f, s2 = 0.f, s3 = 0.f;
#pragma unroll
        for (int i = 0; i < 16; ++i) {
            float4 v = row[i];
            s0 = fmaf(v.x, v.x, s0);
            s1 = fmaf(v.y, v.y, s1);
            s2 = fmaf(v.z, v.z, s2);
            s3 = fmaf(v.w, v.w, s3);
        }
        ws[k] = (s0 + s1) + (s2 + s3);
        ws[K_CODES + k] = 0.0f;
    }
}

// main kernel: one thread per spatial position. x held in 4 ext-vector SSA
// values (va/vb/vc/vd = components 0..3 of each float4 group) with ONLY
// compile-time-constant subscripts -> no alloca, no scratch (r1/r2 spilled:
// VGPR=56 both rounds because SROA can't split a loop-indexed float[64]).
__global__ __launch_bounds__(256, 1) void vq_main(
    const float* __restrict__ in, const float* __restrict__ cb,
    float* __restrict__ out, float* __restrict__ ws) {
    const float* __restrict__ c2 = ws;
    float* hist = ws + K_CODES;

    int n  = blockIdx.x * 256 + threadIdx.x;   // n = b*HW + hw
    int b  = n >> 12;                          // / 4096
    int hw = n & 4095;
    const float* xb = in + (size_t)b * CHW + hw;

    f32x16 va, vb, vc, vd;
    // x[4i+j]: va[i]=x[4i], vb[i]=x[4i+1], vc[i]=x[4i+2], vd[i]=x[4i+3]
#define LDI(i) \
    va[i] = xb[(size_t)(4 * i + 0) * HW]; \
    vb[i] = xb[(size_t)(4 * i + 1) * HW]; \
    vc[i] = xb[(size_t)(4 * i + 2) * HW]; \
    vd[i] = xb[(size_t)(4 * i + 3) * HW];
    REPEAT16(LDI)
#undef LDI

    // x2 = sum x^2, 4 partials, same accumulation order as round 1 (exact)
    float s0 = 0.f, s1 = 0.f, s2 = 0.f, s3 = 0.f;
#define SQI(i) \
    s0 = fmaf(va[i], va[i], s0); \
    s1 = fmaf(vb[i], vb[i], s1); \
    s2 = fmaf(vc[i], vc[i], s2); \
    s3 = fmaf(vd[i], vd[i], s3);
    REPEAT16(SQI)
#undef SQI
    float x2 = (s0 + s1) + (s2 + s3);

    float best = INFINITY;
    int   bidx = 0;
#pragma unroll 4
    for (int k = 0; k < K_CODES; ++k) {
        // wave-uniform address -> scalarized codebook row loads
        const float4* crow = reinterpret_cast<const float4*>(cb + k * D_DIM);
        float d0 = 0.f, d1 = 0.f, d2 = 0.f, d3 = 0.f;
#define DOTI(i) { \
        float4 v = crow[i]; \
        d0 = fmaf(va[i], v.x, d0); \
        d1 = fmaf(vb[i], v.y, d1); \
        d2 = fmaf(vc[i], v.z, d2); \
        d3 = fmaf(vd[i], v.w, d3); }
        REPEAT16(DOTI)
#undef DOTI
        float dot  = (d0 + d1) + (d2 + d3);
        float dist = (x2 - 2.0f * dot) + c2[k];
        bool m = dist < best;          // strict < keeps first index on ties
        best = m ? dist : best;
        bidx = m ? k : bidx;
    }

    // quantized = x + (q - x), written NCHW (coalesced per channel)
    float* ob = out + (size_t)b * CHW + hw;
    const float* __restrict__ q = cb + bidx * D_DIM;
#define STI(i) { \
    float q0 = q[4 * i + 0], q1 = q[4 * i + 1], q2 = q[4 * i + 2], q3 = q[4 * i + 3]; \
    ob[(size_t)(4 * i + 0) * HW] = va[i] + (q0 - va[i]); \
    ob[(size_t)(4 * i + 1) * HW] = vb[i] + (q1 - vb[i]); \
    ob[(size_t)(4 * i + 2) * HW] = vc[i] + (q2 - vc[i]); \
    ob[(size_t)(4 * i + 3) * HW] = vd[i] + (q3 - vd[i]); }
    REPEAT16(STI)
#undef STI

    atomicAdd(&hist[bidx], 1.0f);
}

// perplexity: one block, 1024 threads (16 waves)
__global__ void vq_ppl(const float* __restrict__ ws, float* __restrict__ outp) {
    __shared__ float red[16];
    int t = threadIdx.x;
    float e = ws[K_CODES + t] * (1.0f / (float)NPOS);
    float term = e * logf(e + 1e-10f);
#pragma unroll
    for (int off = 32; off > 0; off >>= 1)
        term += __shfl_down(term, off, 64);
    int lane = t & 63, wid = t >> 6;
    if (lane == 0) red[wid] = term;
    __syncthreads();
    if (t == 0) {
        float s = 0.f;
#pragma unroll
        for (int i = 0; i < 16; ++i) s += red[i];
        *outp = expf(-s);
    }
}

extern "C" void kernel_launch(void* const* d_in, const int* in_sizes, int n_in,
                              void* d_out, int out_size, void* d_ws, size_t ws_size,
                              hipStream_t stream) {
    const float* in = (const float*)d_in[0];   // [32,64,64,64] fp32
    const float* cb = (const float*)d_in[1];   // [1024,64] fp32
    float* out = (float*)d_out;                // quantized [8388608] + ppl [1]
    float* ws  = (float*)d_ws;

    vq_prep<<<4, 256, 0, stream>>>(cb, ws);
    vq_main<<<NPOS / 256, 256, 0, stream>>>(in, cb, out, ws);
    vq_ppl<<<1, 1024, 0, stream>>>(ws, out + (size_t)8388608);
}

// Round 6
// 529.736 us; speedup vs baseline: 1.1796x; 1.1695x over previous
//
#include <hip/hip_runtime.h>
#include <math.h>

// Problem constants (from reference): B=32, C=D=64, H=W=64, K=1024
constexpr int K_CODES = 1024;
constexpr int D_DIM   = 64;
constexpr int HW      = 64 * 64;          // 4096
constexpr int NPOS    = 32 * HW;          // 131072 positions
constexpr int CHW     = D_DIM * HW;       // 262144 (per-batch stride)

typedef float f32x16 __attribute__((ext_vector_type(16)));

#define REPEAT16(M) M(0) M(1) M(2) M(3) M(4) M(5) M(6) M(7) \
                    M(8) M(9) M(10) M(11) M(12) M(13) M(14) M(15)

// ws layout (floats): [0..1023] c2 (codebook squared norms), [1024..2047] histogram
__global__ void vq_prep(const float* __restrict__ cb, float* __restrict__ ws) {
    int k = blockIdx.x * blockDim.x + threadIdx.x;
    if (k < K_CODES) {
        const float4* row = reinterpret_cast<const float4*>(cb + k * D_DIM);
        float s0 = 0.f, s1 = 0.f, s2 = 0.f, s3 = 0.f;
#pragma unroll
        for (int i = 0; i < 16; ++i) {
            float4 v = row[i];
            s0 = fmaf(v.x, v.x, s0);
            s1 = fmaf(v.y, v.y, s1);
            s2 = fmaf(v.z, v.z, s2);
            s3 = fmaf(v.w, v.w, s3);
        }
        ws[k] = (s0 + s1) + (s2 + s3);
        ws[K_CODES + k] = 0.0f;
    }
}

// One thread per spatial position, x in 4× f32x16 SSA values.
// KEY FIX: amdgpu_waves_per_eu(1,2). The backend register-allocates for the
// MAX of the waves/EU range (default 8 -> 64-VGPR target -> it spilled x to
// scratch; VGPR_Count was 56 in rounds 1/2/4 regardless of source form).
// Our grid (512 blocks) can only occupy 2 waves/EU anyway, so capping the
// target at 2 costs nothing and raises the VGPR budget to 256.
__global__ __launch_bounds__(256)
__attribute__((amdgpu_waves_per_eu(1, 2)))
void vq_main(
    const float* __restrict__ in, const float* __restrict__ cb,
    float* __restrict__ out, float* __restrict__ ws) {
    const float* __restrict__ c2 = ws;
    float* hist = ws + K_CODES;

    int n  = blockIdx.x * 256 + threadIdx.x;   // n = b*HW + hw
    int b  = n >> 12;                          // / 4096
    int hw = n & 4095;
    const float* xb = in + (size_t)b * CHW + hw;

    f32x16 va, vb, vc, vd;
    // x[4i+j]: va[i]=x[4i], vb[i]=x[4i+1], vc[i]=x[4i+2], vd[i]=x[4i+3]
#define LDI(i) \
    va[i] = xb[(size_t)(4 * i + 0) * HW]; \
    vb[i] = xb[(size_t)(4 * i + 1) * HW]; \
    vc[i] = xb[(size_t)(4 * i + 2) * HW]; \
    vd[i] = xb[(size_t)(4 * i + 3) * HW];
    REPEAT16(LDI)
#undef LDI

    // x2 = sum x^2, 4 partials, same accumulation order as round 1 (exact)
    float s0 = 0.f, s1 = 0.f, s2 = 0.f, s3 = 0.f;
#define SQI(i) \
    s0 = fmaf(va[i], va[i], s0); \
    s1 = fmaf(vb[i], vb[i], s1); \
    s2 = fmaf(vc[i], vc[i], s2); \
    s3 = fmaf(vd[i], vd[i], s3);
    REPEAT16(SQI)
#undef SQI
    float x2 = (s0 + s1) + (s2 + s3);

    float best = INFINITY;
    int   bidx = 0;
    for (int k = 0; k < K_CODES; ++k) {
        // wave-uniform address -> scalarized codebook row loads
        const float4* crow = reinterpret_cast<const float4*>(cb + k * D_DIM);
        float d0 = 0.f, d1 = 0.f, d2 = 0.f, d3 = 0.f;
#define DOTI(i) { \
        float4 v = crow[i]; \
        d0 = fmaf(va[i], v.x, d0); \
        d1 = fmaf(vb[i], v.y, d1); \
        d2 = fmaf(vc[i], v.z, d2); \
        d3 = fmaf(vd[i], v.w, d3); }
        REPEAT16(DOTI)
#undef DOTI
        float dot  = (d0 + d1) + (d2 + d3);
        float dist = (x2 - 2.0f * dot) + c2[k];
        bool m = dist < best;          // strict < keeps first index on ties
        best = m ? dist : best;
        bidx = m ? k : bidx;
    }

    // quantized = x + (q - x), written NCHW (coalesced per channel)
    float* ob = out + (size_t)b * CHW + hw;
    const float* __restrict__ q = cb + bidx * D_DIM;
#define STI(i) { \
    float q0 = q[4 * i + 0], q1 = q[4 * i + 1], q2 = q[4 * i + 2], q3 = q[4 * i + 3]; \
    ob[(size_t)(4 * i + 0) * HW] = va[i] + (q0 - va[i]); \
    ob[(size_t)(4 * i + 1) * HW] = vb[i] + (q1 - vb[i]); \
    ob[(size_t)(4 * i + 2) * HW] = vc[i] + (q2 - vc[i]); \
    ob[(size_t)(4 * i + 3) * HW] = vd[i] + (q3 - vd[i]); }
    REPEAT16(STI)
#undef STI

    atomicAdd(&hist[bidx], 1.0f);
}

// perplexity: one block, 1024 threads (16 waves)
__global__ void vq_ppl(const float* __restrict__ ws, float* __restrict__ outp) {
    __shared__ float red[16];
    int t = threadIdx.x;
    float e = ws[K_CODES + t] * (1.0f / (float)NPOS);
    float term = e * logf(e + 1e-10f);
#pragma unroll
    for (int off = 32; off > 0; off >>= 1)
        term += __shfl_down(term, off, 64);
    int lane = t & 63, wid = t >> 6;
    if (lane == 0) red[wid] = term;
    __syncthreads();
    if (t == 0) {
        float s = 0.f;
#pragma unroll
        for (int i = 0; i < 16; ++i) s += red[i];
        *outp = expf(-s);
    }
}

extern "C" void kernel_launch(void* const* d_in, const int* in_sizes, int n_in,
                              void* d_out, int out_size, void* d_ws, size_t ws_size,
                              hipStream_t stream) {
    const float* in = (const float*)d_in[0];   // [32,64,64,64] fp32
    const float* cb = (const float*)d_in[1];   // [1024,64] fp32
    float* out = (float*)d_out;                // quantized [8388608] + ppl [1]
    float* ws  = (float*)d_ws;

    vq_prep<<<4, 256, 0, stream>>>(cb, ws);
    vq_main<<<NPOS / 256, 256, 0, stream>>>(in, cb, out, ws);
    vq_ppl<<<1, 1024, 0, stream>>>(ws, out + (size_t)8388608);
}

// Round 7
// 470.859 us; speedup vs baseline: 1.3271x; 1.1250x over previous
//
#include <hip/hip_runtime.h>
#include <math.h>

// Problem constants (from reference): B=32, C=D=64, H=W=64, K=1024
constexpr int K_CODES = 1024;
constexpr int D_DIM   = 64;
constexpr int HW      = 64 * 64;          // 4096
constexpr int NPOS    = 32 * HW;          // 131072 positions
constexpr int CHW     = D_DIM * HW;       // 262144 (per-batch stride)
constexpr int CHUNK   = 128;              // codes per LDS chunk (32 KB)
constexpr int NCHUNK  = K_CODES / CHUNK;  // 8

typedef float f32x16 __attribute__((ext_vector_type(16)));

#define REPEAT16(M) M(0) M(1) M(2) M(3) M(4) M(5) M(6) M(7) \
                    M(8) M(9) M(10) M(11) M(12) M(13) M(14) M(15)

// ws layout (floats): [0..1023] c2 (codebook squared norms), [1024..2047] histogram
__global__ void vq_prep(const float* __restrict__ cb, float* __restrict__ ws) {
    int k = blockIdx.x * blockDim.x + threadIdx.x;
    if (k < K_CODES) {
        const float4* row = reinterpret_cast<const float4*>(cb + k * D_DIM);
        float s0 = 0.f, s1 = 0.f, s2 = 0.f, s3 = 0.f;
#pragma unroll
        for (int i = 0; i < 16; ++i) {
            float4 v = row[i];
            s0 = fmaf(v.x, v.x, s0);
            s1 = fmaf(v.y, v.y, s1);
            s2 = fmaf(v.z, v.z, s2);
            s3 = fmaf(v.w, v.w, s3);
        }
        ws[k] = (s0 + s1) + (s2 + s3);
        ws[K_CODES + k] = 0.0f;
    }
}

// One thread per position. Codebook staged through LDS in 8 chunks of 128
// codes: r1-r6 showed the bottleneck is exposed L2 latency on per-iteration
// codebook loads (562 cy/iter vs 128 cy FMA, VALUBusy 28-30%, only 2
// waves/SIMD to hide it). LDS ds_read_b128 at wave-uniform addresses
// (broadcast, conflict-free) lets the compiler lgkmcnt-pipeline reads under
// the FMA stream. Distance math order unchanged (absmax was 0.0).
__global__ __launch_bounds__(256)
__attribute__((amdgpu_waves_per_eu(1, 2)))
void vq_main(
    const float* __restrict__ in, const float* __restrict__ cb,
    float* __restrict__ out, float* __restrict__ ws) {
    const float* __restrict__ c2 = ws;
    float* hist = ws + K_CODES;

    __shared__ float4 cbs[CHUNK * 16];     // 128 codes x 64 floats = 32 KB

    int n  = blockIdx.x * 256 + threadIdx.x;   // n = b*HW + hw
    int b  = n >> 12;                          // / 4096
    int hw = n & 4095;
    const float* xb = in + (size_t)b * CHW + hw;

    f32x16 va, vb, vc, vd;
    // x[4i+j]: va[i]=x[4i], vb[i]=x[4i+1], vc[i]=x[4i+2], vd[i]=x[4i+3]
#define LDI(i) \
    va[i] = xb[(size_t)(4 * i + 0) * HW]; \
    vb[i] = xb[(size_t)(4 * i + 1) * HW]; \
    vc[i] = xb[(size_t)(4 * i + 2) * HW]; \
    vd[i] = xb[(size_t)(4 * i + 3) * HW];
    REPEAT16(LDI)
#undef LDI

    // x2 = sum x^2, 4 partials, same accumulation order as round 1 (exact)
    float s0 = 0.f, s1 = 0.f, s2 = 0.f, s3 = 0.f;
#define SQI(i) \
    s0 = fmaf(va[i], va[i], s0); \
    s1 = fmaf(vb[i], vb[i], s1); \
    s2 = fmaf(vc[i], vc[i], s2); \
    s3 = fmaf(vd[i], vd[i], s3);
    REPEAT16(SQI)
#undef SQI
    float x2 = (s0 + s1) + (s2 + s3);

    float best = INFINITY;
    int   bidx = 0;

    for (int ch = 0; ch < NCHUNK; ++ch) {
        __syncthreads();   // previous chunk fully consumed before overwrite
        // stage chunk: 2048 float4 / 256 threads = 8 float4 each, coalesced
        const float4* src = reinterpret_cast<const float4*>(cb) + ch * (CHUNK * 16);
#pragma unroll
        for (int j = 0; j < 8; ++j)
            cbs[threadIdx.x + j * 256] = src[threadIdx.x + j * 256];
        __syncthreads();

#pragma unroll 2
        for (int kk = 0; kk < CHUNK; ++kk) {
            int k = ch * CHUNK + kk;
            const float4* crow = &cbs[kk * 16];   // wave-uniform -> broadcast
            float d0 = 0.f, d1 = 0.f, d2 = 0.f, d3 = 0.f;
#define DOTI(i) { \
            float4 v = crow[i]; \
            d0 = fmaf(va[i], v.x, d0); \
            d1 = fmaf(vb[i], v.y, d1); \
            d2 = fmaf(vc[i], v.z, d2); \
            d3 = fmaf(vd[i], v.w, d3); }
            REPEAT16(DOTI)
#undef DOTI
            float dot  = (d0 + d1) + (d2 + d3);
            float dist = (x2 - 2.0f * dot) + c2[k];
            bool m = dist < best;      // strict < keeps first index on ties
            best = m ? dist : best;
            bidx = m ? k : bidx;
        }
    }

    // quantized = x + (q - x), written NCHW (coalesced per channel)
    float* ob = out + (size_t)b * CHW + hw;
    const float* __restrict__ q = cb + bidx * D_DIM;
#define STI(i) { \
    float q0 = q[4 * i + 0], q1 = q[4 * i + 1], q2 = q[4 * i + 2], q3 = q[4 * i + 3]; \
    ob[(size_t)(4 * i + 0) * HW] = va[i] + (q0 - va[i]); \
    ob[(size_t)(4 * i + 1) * HW] = vb[i] + (q1 - vb[i]); \
    ob[(size_t)(4 * i + 2) * HW] = vc[i] + (q2 - vc[i]); \
    ob[(size_t)(4 * i + 3) * HW] = vd[i] + (q3 - vd[i]); }
    REPEAT16(STI)
#undef STI

    atomicAdd(&hist[bidx], 1.0f);
}

// perplexity: one block, 1024 threads (16 waves)
__global__ void vq_ppl(const float* __restrict__ ws, float* __restrict__ outp) {
    __shared__ float red[16];
    int t = threadIdx.x;
    float e = ws[K_CODES + t] * (1.0f / (float)NPOS);
    float term = e * logf(e + 1e-10f);
#pragma unroll
    for (int off = 32; off > 0; off >>= 1)
        term += __shfl_down(term, off, 64);
    int lane = t & 63, wid = t >> 6;
    if (lane == 0) red[wid] = term;
    __syncthreads();
    if (t == 0) {
        float s = 0.f;
#pragma unroll
        for (int i = 0; i < 16; ++i) s += red[i];
        *outp = expf(-s);
    }
}

extern "C" void kernel_launch(void* const* d_in, const int* in_sizes, int n_in,
                              void* d_out, int out_size, void* d_ws, size_t ws_size,
                              hipStream_t stream) {
    const float* in = (const float*)d_in[0];   // [32,64,64,64] fp32
    const float* cb = (const float*)d_in[1];   // [1024,64] fp32
    float* out = (float*)d_out;                // quantized [8388608] + ppl [1]
    float* ws  = (float*)d_ws;

    vq_prep<<<4, 256, 0, stream>>>(cb, ws);
    vq_main<<<NPOS / 256, 256, 0, stream>>>(in, cb, out, ws);
    vq_ppl<<<1, 1024, 0, stream>>>(ws, out + (size_t)8388608);
}